// Round 4
// baseline (576.637 us; speedup 1.0000x reference)
//
#include <hip/hip_runtime.h>
#include <math.h>

#define B_ROWS 512
#define D_DIM  512
#define C_CLS  100000
#define SCALE  64.0f
#define EPSN   1e-12f

#define BM 128
#define BN 64
#define NT 1563              // ceil(100000/64) column tiles = partials per row

typedef __attribute__((ext_vector_type(8))) short bf16x8;
typedef __attribute__((ext_vector_type(4))) float f32x4;

__device__ inline unsigned short f2bf(float f) {
    union { float f; unsigned int u; } v; v.f = f;
    unsigned int r = v.u + 0x7fffu + ((v.u >> 16) & 1u);
    return (unsigned short)(r >> 16);
}
__device__ inline float bf2f(unsigned short h) {
    union { unsigned int u; float f; } v; v.u = ((unsigned int)h) << 16;
    return v.f;
}

// ---------- normalize x rows, store bf16 ----------
__global__ void normalize_x(const float* __restrict__ x, unsigned short* __restrict__ xnb) {
    int row  = blockIdx.x;
    int lane = threadIdx.x;  // 64
    const float4* xr = (const float4*)(x + (size_t)row * D_DIM);
    float4 a = xr[lane];
    float4 b = xr[lane + 64];
    float ss = a.x*a.x + a.y*a.y + a.z*a.z + a.w*a.w
             + b.x*b.x + b.y*b.y + b.z*b.z + b.w*b.w;
    #pragma unroll
    for (int m = 1; m < 64; m <<= 1) ss += __shfl_xor(ss, m);
    float inv = 1.0f / fmaxf(sqrtf(ss), EPSN);
    ushort4 o0, o1;
    o0.x = f2bf(a.x*inv); o0.y = f2bf(a.y*inv); o0.z = f2bf(a.z*inv); o0.w = f2bf(a.w*inv);
    o1.x = f2bf(b.x*inv); o1.y = f2bf(b.y*inv); o1.z = f2bf(b.z*inv); o1.w = f2bf(b.w*inv);
    ushort4* orow = (ushort4*)(xnb + (size_t)row * D_DIM);
    orow[lane]      = o0;
    orow[lane + 64] = o1;
}

// ---------- W prep: wn[c,:] = w[c,:] * S / ||w[c,:]||, bf16 ----------
__global__ void w_prep(const float* __restrict__ w, unsigned short* __restrict__ wn) {
    int c    = blockIdx.x * 4 + (threadIdx.x >> 6);
    int lane = threadIdx.x & 63;
    const float4* wr = (const float4*)(w + (size_t)c * D_DIM);
    float4 a = wr[lane];
    float4 b = wr[lane + 64];
    float ss = a.x*a.x + a.y*a.y + a.z*a.z + a.w*a.w
             + b.x*b.x + b.y*b.y + b.z*b.z + b.w*b.w;
    #pragma unroll
    for (int m = 1; m < 64; m <<= 1) ss += __shfl_xor(ss, m);
    float s = SCALE / fmaxf(sqrtf(ss), EPSN);
    ushort4 o0, o1;
    o0.x = f2bf(a.x*s); o0.y = f2bf(a.y*s); o0.z = f2bf(a.z*s); o0.w = f2bf(a.w*s);
    o1.x = f2bf(b.x*s); o1.y = f2bf(b.y*s); o1.z = f2bf(b.z*s); o1.w = f2bf(b.w*s);
    ushort4* orow = (ushort4*)(wn + (size_t)c * D_DIM);
    orow[lane]      = o0;
    orow[lane + 64] = o1;
}

// ---------- barrier-free MFMA GEMM: A in registers (full K), B global->reg ----------
// Block: 4 waves; wave w owns rows m0 + w*32 .. +31 and ALL 64 cols of the tile.
// A frag  [row=lane&15][k=quad*8]  (16B aligned global load, 32 frags = 128 VGPR)
// B frag  [col=lane&15][k=quad*8]  (16B aligned global load, no LDS round-trip)
// C tile  col=lane&15, row=quad*4+reg
__global__ __launch_bounds__(256, 2) void gemm_ce(const unsigned short* __restrict__ xnb,
                                                  const unsigned short* __restrict__ wn,
                                                  float2* __restrict__ partials) {
    int tid  = threadIdx.x;
    int w    = tid >> 6;
    int lane = tid & 63;
    int quad = lane >> 4;
    int lr   = lane & 15;
    int m0   = blockIdx.x * BM;
    int ct   = blockIdx.y;
    int c0   = ct * BN;

    // ---- load A fragments for this wave's 32 rows, full K ----
    bf16x8 A[2][16];
    #pragma unroll
    for (int rf = 0; rf < 2; rf++) {
        const unsigned short* arow =
            xnb + (size_t)(m0 + w * 32 + rf * 16 + lr) * D_DIM + quad * 8;
        #pragma unroll
        for (int ks = 0; ks < 16; ks++)
            A[rf][ks] = *(const bf16x8*)(arow + ks * 32);
    }

    // ---- B row pointers for the 4 col-fragments ----
    const unsigned short* brow[4];
    int valid[4];
    #pragma unroll
    for (int cf = 0; cf < 4; cf++) {
        int c = c0 + cf * 16 + lr;
        valid[cf] = (c < C_CLS);
        brow[cf] = wn + (size_t)(valid[cf] ? c : (C_CLS - 1)) * D_DIM + quad * 8;
    }

    f32x4 acc[2][4];
    #pragma unroll
    for (int rf = 0; rf < 2; rf++)
        #pragma unroll
        for (int cf = 0; cf < 4; cf++) {
            acc[rf][cf][0] = 0.f; acc[rf][cf][1] = 0.f;
            acc[rf][cf][2] = 0.f; acc[rf][cf][3] = 0.f;
        }

    // ---- barrier-free K loop: 64 independent 16B loads, 128 MFMA ----
    #pragma unroll
    for (int ks = 0; ks < 16; ks++) {
        bf16x8 b0 = *(const bf16x8*)(brow[0] + ks * 32);
        bf16x8 b1 = *(const bf16x8*)(brow[1] + ks * 32);
        bf16x8 b2 = *(const bf16x8*)(brow[2] + ks * 32);
        bf16x8 b3 = *(const bf16x8*)(brow[3] + ks * 32);
        #pragma unroll
        for (int rf = 0; rf < 2; rf++) {
            acc[rf][0] = __builtin_amdgcn_mfma_f32_16x16x32_bf16(A[rf][ks], b0, acc[rf][0], 0, 0, 0);
            acc[rf][1] = __builtin_amdgcn_mfma_f32_16x16x32_bf16(A[rf][ks], b1, acc[rf][1], 0, 0, 0);
            acc[rf][2] = __builtin_amdgcn_mfma_f32_16x16x32_bf16(A[rf][ks], b2, acc[rf][2], 0, 0, 0);
            acc[rf][3] = __builtin_amdgcn_mfma_f32_16x16x32_bf16(A[rf][ks], b3, acc[rf][3], 0, 0, 0);
        }
    }

    // ---- epilogue: per-row online-softmax partial over this tile's 64 cols ----
    #pragma unroll
    for (int rf = 0; rf < 2; rf++) {
        #pragma unroll
        for (int r = 0; r < 4; r++) {
            int row_g = m0 + w * 32 + rf * 16 + quad * 4 + r;
            float v0 = valid[0] ? acc[rf][0][r] : -1e30f;
            float v1 = valid[1] ? acc[rf][1][r] : -1e30f;
            float v2 = valid[2] ? acc[rf][2][r] : -1e30f;
            float v3 = valid[3] ? acc[rf][3][r] : -1e30f;
            float m = fmaxf(fmaxf(v0, v1), fmaxf(v2, v3));
            #pragma unroll
            for (int msk = 1; msk < 16; msk <<= 1) m = fmaxf(m, __shfl_xor(m, msk));
            float s = expf(v0 - m) + expf(v1 - m) + expf(v2 - m) + expf(v3 - m);
            #pragma unroll
            for (int msk = 1; msk < 16; msk <<= 1) s += __shfl_xor(s, msk);
            if (lr == 0)
                partials[(size_t)row_g * NT + ct] = make_float2(m, s);
        }
    }
}

// ---------- fused: label logit + merge partials -> LSE -> mean NLL ----------
__global__ void reduce_loss(const float2* __restrict__ partials,
                            const unsigned short* __restrict__ xnb,
                            const unsigned short* __restrict__ wn,
                            const int* __restrict__ label,
                            float* __restrict__ out) {
    __shared__ float sm[256], ssum[256], sdot[256];
    int row = blockIdx.x, tid = threadIdx.x;

    // label-logit partial: 128 threads x ushort4 covers D=512
    float d = 0.f;
    int lab = label[row];
    if (tid < 128) {
        ushort4 xv = ((const ushort4*)(xnb + (size_t)row * D_DIM))[tid];
        ushort4 wv = ((const ushort4*)(wn + (size_t)lab * D_DIM))[tid];
        d = bf2f(xv.x) * bf2f(wv.x) + bf2f(xv.y) * bf2f(wv.y)
          + bf2f(xv.z) * bf2f(wv.z) + bf2f(xv.w) * bf2f(wv.w);
    }
    sdot[tid] = d;

    // online merge of this row's partials (coalesced: lane-stride 8B)
    float m = -INFINITY, s = 0.f;
    for (int idx = tid; idx < NT; idx += 256) {
        float2 p = partials[(size_t)row * NT + idx];
        if (p.x > m) { s = s * expf(m - p.x) + p.y; m = p.x; }
        else         { s += p.y * expf(p.x - m); }
    }
    sm[tid] = m; ssum[tid] = s;
    __syncthreads();
    for (int off = 128; off > 0; off >>= 1) {
        if (tid < off) {
            float m2 = sm[tid + off], s2 = ssum[tid + off];
            float mm = fmaxf(m, m2);
            s = s * expf(m - mm) + s2 * expf(m2 - mm);
            m = mm;
            sm[tid] = m; ssum[tid] = s;
            sdot[tid] += sdot[tid + off];
        }
        __syncthreads();
    }
    if (tid == 0) {
        float lse = m + logf(s);
        atomicAdd(out, (lse - sdot[0]) * (1.0f / (float)B_ROWS));
    }
}

extern "C" void kernel_launch(void* const* d_in, const int* in_sizes, int n_in,
                              void* d_out, int out_size, void* d_ws, size_t ws_size,
                              hipStream_t stream) {
    const float* x     = (const float*)d_in[0];
    const float* w     = (const float*)d_in[1];
    const int*   label = (const int*)d_in[2];
    float* out = (float*)d_out;

    char* ws = (char*)d_ws;
    unsigned short* xnb = (unsigned short*)ws;                 // 524288 B
    float2* partials    = (float2*)(ws + 524288);              // 512*1563*8 = 6402048 B (ends 6926336)
    unsigned short* wn  = (unsigned short*)(ws + 6926336);     // 102400000 B (ends 109326336)

    hipMemsetAsync(d_out, 0, sizeof(float), stream);
    normalize_x<<<B_ROWS, 64, 0, stream>>>(x, xnb);
    w_prep<<<C_CLS / 4, 256, 0, stream>>>(w, wn);
    gemm_ce<<<dim3(4, NT), 256, 0, stream>>>(xnb, wn, partials);
    reduce_loss<<<B_ROWS, 256, 0, stream>>>(partials, xnb, wn, label, out);
}

// Round 5
// 426.313 us; speedup vs baseline: 1.3526x; 1.3526x over previous
//
#include <hip/hip_runtime.h>
#include <math.h>

#define B_ROWS 512
#define D_DIM  512
#define C_CLS  100000
#define SCALE  64.0f
#define EPSN   1e-12f

#define NT 1563              // ceil(100000/64) col tiles; partials per row

typedef __attribute__((ext_vector_type(8))) short bf16x8;
typedef __attribute__((ext_vector_type(4))) float f32x4;

__device__ inline unsigned short f2bf(float f) {
    union { float f; unsigned int u; } v; v.f = f;
    unsigned int r = v.u + 0x7fffu + ((v.u >> 16) & 1u);
    return (unsigned short)(r >> 16);
}
__device__ inline float bf2f(unsigned short h) {
    union { unsigned int u; float f; } v; v.u = ((unsigned int)h) << 16;
    return v.f;
}

// ---------- fused prep: blocks [0,2048) scale-normalize W -> bf16,
//            blocks [2048,2176) normalize x -> bf16. Grid-stride, persistent waves.
__global__ void prep(const float* __restrict__ w, const float* __restrict__ x,
                     unsigned short* __restrict__ wn, unsigned short* __restrict__ xnb) {
    int wid  = threadIdx.x >> 6;
    int lane = threadIdx.x & 63;
    int bid  = blockIdx.x;
    if (bid < 2048) {
        for (int c = bid * 4 + wid; c < C_CLS; c += 8192) {
            const float4* wr = (const float4*)(w + (size_t)c * D_DIM);
            float4 a = wr[lane];
            float4 b = wr[lane + 64];
            float ss = a.x*a.x + a.y*a.y + a.z*a.z + a.w*a.w
                     + b.x*b.x + b.y*b.y + b.z*b.z + b.w*b.w;
            #pragma unroll
            for (int m = 1; m < 64; m <<= 1) ss += __shfl_xor(ss, m);
            float s = SCALE / fmaxf(sqrtf(ss), EPSN);
            ushort4 o0, o1;
            o0.x = f2bf(a.x*s); o0.y = f2bf(a.y*s); o0.z = f2bf(a.z*s); o0.w = f2bf(a.w*s);
            o1.x = f2bf(b.x*s); o1.y = f2bf(b.y*s); o1.z = f2bf(b.z*s); o1.w = f2bf(b.w*s);
            ushort4* orow = (ushort4*)(wn + (size_t)c * D_DIM);
            orow[lane]      = o0;
            orow[lane + 64] = o1;
        }
    } else {
        int r = (bid - 2048) * 4 + wid;   // 128 blocks x 4 waves = 512 rows
        const float4* xr = (const float4*)(x + (size_t)r * D_DIM);
        float4 a = xr[lane];
        float4 b = xr[lane + 64];
        float ss = a.x*a.x + a.y*a.y + a.z*a.z + a.w*a.w
                 + b.x*b.x + b.y*b.y + b.z*b.z + b.w*b.w;
        #pragma unroll
        for (int m = 1; m < 64; m <<= 1) ss += __shfl_xor(ss, m);
        float s = 1.0f / fmaxf(sqrtf(ss), EPSN);
        ushort4 o0, o1;
        o0.x = f2bf(a.x*s); o0.y = f2bf(a.y*s); o0.z = f2bf(a.z*s); o0.w = f2bf(a.w*s);
        o1.x = f2bf(b.x*s); o1.y = f2bf(b.y*s); o1.z = f2bf(b.z*s); o1.w = f2bf(b.w*s);
        ushort4* orow = (ushort4*)(xnb + (size_t)r * D_DIM);
        orow[lane]      = o0;
        orow[lane + 64] = o1;
    }
}

// ---------- persistent MFMA GEMM: A (64 rows x K=512) in LDS, one barrier.
// Each wave independently processes 64-col tiles: B global->reg, A via ds_read.
// Grid 512 = (xcd:8) x (rowgroup:8) x (colslice:8); 8 waves/block.
// A LDS swizzle: row r, 16B-chunk c stored at slot c ^ (r&7)  -> uniform banks.
__global__ __launch_bounds__(512, 4) void gemm_ce(const unsigned short* __restrict__ xnb,
                                                  const unsigned short* __restrict__ wn,
                                                  float* __restrict__ partials) {
    __shared__ unsigned short Ash[64 * 512];   // 64 KB

    int tid  = threadIdx.x;
    int bid  = blockIdx.x;
    int x    = bid & 7;          // XCD (round-robin dispatch)
    int rg   = (bid >> 3) & 7;   // row group: rows rg*64 .. +63
    int cs   = bid >> 6;         // col slice 0..7
    int wid  = tid >> 6;
    int lane = tid & 63;
    int quad = lane >> 4;
    int lr   = lane & 15;

    // ---- stage A once: 64 rows x 64 chunks of 16B, xor-swizzled ----
    #pragma unroll
    for (int i = 0; i < 8; i++) {
        int ch = i * 512 + tid;          // 4096 chunks
        int r  = ch >> 6, c = ch & 63;
        *(uint4*)(Ash + r * 512 + ((c ^ (r & 7)) * 8)) =
            *(const uint4*)(xnb + (size_t)(rg * 64 + r) * D_DIM + c * 8);
    }
    __syncthreads();

    int worker = (x * 8 + cs) * 8 + wid;   // 0..511 within this rowgroup

    for (int t = 0; t < 4; t++) {
        int ct = worker + t * 512;
        if (ct >= NT) break;
        int c0 = ct * 64;

        const unsigned short* brow[4];
        int valid[4];
        #pragma unroll
        for (int cf = 0; cf < 4; cf++) {
            int c = c0 + cf * 16 + lr;
            valid[cf] = (c < C_CLS);
            brow[cf] = wn + (size_t)(valid[cf] ? c : (C_CLS - 1)) * D_DIM + quad * 8;
        }

        f32x4 acc[4][4];
        #pragma unroll
        for (int rf = 0; rf < 4; rf++)
            #pragma unroll
            for (int cf = 0; cf < 4; cf++) {
                acc[rf][cf][0] = 0.f; acc[rf][cf][1] = 0.f;
                acc[rf][cf][2] = 0.f; acc[rf][cf][3] = 0.f;
            }

        #pragma unroll 4
        for (int ks = 0; ks < 16; ks++) {
            bf16x8 b0 = *(const bf16x8*)(brow[0] + ks * 32);
            bf16x8 b1 = *(const bf16x8*)(brow[1] + ks * 32);
            bf16x8 b2 = *(const bf16x8*)(brow[2] + ks * 32);
            bf16x8 b3 = *(const bf16x8*)(brow[3] + ks * 32);
            #pragma unroll
            for (int rf = 0; rf < 4; rf++) {
                int r = rf * 16 + lr;
                bf16x8 a = *(const bf16x8*)(Ash + r * 512 + (((ks * 4 + quad) ^ (r & 7)) * 8));
                acc[rf][0] = __builtin_amdgcn_mfma_f32_16x16x32_bf16(a, b0, acc[rf][0], 0, 0, 0);
                acc[rf][1] = __builtin_amdgcn_mfma_f32_16x16x32_bf16(a, b1, acc[rf][1], 0, 0, 0);
                acc[rf][2] = __builtin_amdgcn_mfma_f32_16x16x32_bf16(a, b2, acc[rf][2], 0, 0, 0);
                acc[rf][3] = __builtin_amdgcn_mfma_f32_16x16x32_bf16(a, b3, acc[rf][3], 0, 0, 0);
            }
        }

        // epilogue: partial Σexp over this tile's 64 cols (|logit|<=64.2 -> no max needed)
        #pragma unroll
        for (int rf = 0; rf < 4; rf++) {
            #pragma unroll
            for (int rr = 0; rr < 4; rr++) {
                float e = expf(valid[0] ? acc[rf][0][rr] : -1e30f)
                        + expf(valid[1] ? acc[rf][1][rr] : -1e30f)
                        + expf(valid[2] ? acc[rf][2][rr] : -1e30f)
                        + expf(valid[3] ? acc[rf][3][rr] : -1e30f);
                #pragma unroll
                for (int msk = 1; msk < 16; msk <<= 1) e += __shfl_xor(e, msk);
                if (lr == 0) {
                    int row_g = rg * 64 + rf * 16 + quad * 4 + rr;
                    partials[(size_t)row_g * NT + ct] = e;
                }
            }
        }
    }
}

// ---------- fused: label logit + sum partials -> loss ----------
__global__ void reduce_loss(const float* __restrict__ partials,
                            const unsigned short* __restrict__ xnb,
                            const unsigned short* __restrict__ wn,
                            const int* __restrict__ label,
                            float* __restrict__ out) {
    __shared__ float ssum[256], sdot[256];
    int row = blockIdx.x, tid = threadIdx.x;

    float d = 0.f;
    int lab = label[row];
    if (tid < 128) {
        ushort4 xv = ((const ushort4*)(xnb + (size_t)row * D_DIM))[tid];
        ushort4 wv = ((const ushort4*)(wn + (size_t)lab * D_DIM))[tid];
        d = bf2f(xv.x) * bf2f(wv.x) + bf2f(xv.y) * bf2f(wv.y)
          + bf2f(xv.z) * bf2f(wv.z) + bf2f(xv.w) * bf2f(wv.w);
    }
    sdot[tid] = d;

    float s = 0.f;
    for (int idx = tid; idx < NT; idx += 256)
        s += partials[(size_t)row * NT + idx];
    ssum[tid] = s;
    __syncthreads();
    for (int off = 128; off > 0; off >>= 1) {
        if (tid < off) {
            ssum[tid] += ssum[tid + off];
            sdot[tid] += sdot[tid + off];
        }
        __syncthreads();
    }
    if (tid == 0)
        atomicAdd(out, (logf(ssum[0]) - sdot[0]) * (1.0f / (float)B_ROWS));
}

extern "C" void kernel_launch(void* const* d_in, const int* in_sizes, int n_in,
                              void* d_out, int out_size, void* d_ws, size_t ws_size,
                              hipStream_t stream) {
    const float* x     = (const float*)d_in[0];
    const float* w     = (const float*)d_in[1];
    const int*   label = (const int*)d_in[2];
    float* out = (float*)d_out;

    char* ws = (char*)d_ws;
    unsigned short* xnb = (unsigned short*)ws;                 // 524288 B
    float* partials     = (float*)(ws + 524288);               // 512*1563*4 = 3201024 B (ends 3725312)
    unsigned short* wn  = (unsigned short*)(ws + 3725312);     // 102400000 B (ends 106125312)

    hipMemsetAsync(d_out, 0, sizeof(float), stream);
    prep<<<2176, 256, 0, stream>>>(w, x, wn, xnb);
    gemm_ce<<<512, 512, 0, stream>>>(xnb, wn, partials);
    reduce_loss<<<B_ROWS, 256, 0, stream>>>(partials, xnb, wn, label, out);
}